// Round 17
// baseline (170.909 us; speedup 1.0000x reference)
//
#include <hip/hip_runtime.h>
#include <hip/hip_bf16.h>

typedef __bf16 bf16;
typedef __bf16 bf16x8 __attribute__((ext_vector_type(8)));
typedef float f32x4 __attribute__((ext_vector_type(4)));

#define C_DIM 128
#define LDA 136   // sA/sY row stride (bf16 elems)
#define LDQ 40    // q/k row stride
#define LDVT 72   // vT row stride
#define LDP 72    // P row stride
#define LDH 264   // h-half row stride

__device__ __forceinline__ f32x4 mfma16(bf16x8 a, bf16x8 b, f32x4 c) {
  return __builtin_amdgcn_mfma_f32_16x16x32_bf16(a, b, c, 0, 0, 0);
}

// r17 = r16 (166.6us best) + two serial-chain cuts, nothing else:
//  (1) DEFERRED SOFTMAX NORMALIZATION: sP holds unnormalized e=exp(s+bias)
//      (<= e^0.8 ~ 2.2, bf16-safe); inv=1/sum applied at the O-epilogue
//      (O row n = mt*16+lhi*4+r matches softmax row indexing exactly).
//      P-stores no longer wait on the 4-deep shfl reduce + rcp; that chain
//      overlaps PV fragment loads/MFMAs. 32 mults at O replace 64 at P.
//  (2) T5 s_setprio(1) around MFMA clusters — waves are desynced here
//      (same-head QKV, no P2->P3 barrier; 2 blocks/CU interleave), the regime
//      where setprio measured +4-7% (guide m191) vs null in lockstep (m190).
// r15 lesson: never shrink M below 64 (weight-frag reuse). r14: packed-store
// transposes add bank conflicts. r11: 3 blocks/CU always spills, net-negative.
//
// LDS layout (76800 B, 2 blocks/CU at 256 threads):
//   sA  @ 0      : 64x136 bf16 = 17408   xn1 -> O(attn concat) -> xn2
//   R1  @ 17408  : sQ[4][64][40]+sK[4][64][40] -> sP[4][64][72] -> sY -> sH[64][264]
//   sVT @ 58368  : 4x32x72
// Retained: same-head QKV (no P2->P3 barrier), compile-time kind, no-max softmax
// (|scores|<0.4 by construction), sigmoid-GELU, launch_bounds(256,2),
// batch-issued x residual loads, rolling FC2 prefetch.

__global__ __launch_bounds__(256, 2) void swin_fused(
    const float* __restrict__ x,
    const bf16*  __restrict__ Wqkv_t, const float* __restrict__ b_qkv,
    const bf16*  __restrict__ Wout_t, const float* __restrict__ b_out,
    const float* __restrict__ btabx,
    const float* __restrict__ g1, const float* __restrict__ be1,
    const float* __restrict__ g2, const float* __restrict__ be2,
    const bf16*  __restrict__ Wfc1_t, const float* __restrict__ b_fc1,
    const bf16*  __restrict__ Wfc2_t, const float* __restrict__ b_fc2,
    float* __restrict__ out)
{
  __shared__ __attribute__((aligned(16))) char smem[76800];
  bf16 (*sA)[LDA]       = (bf16(*)[LDA])(smem);
  bf16 (*sQ)[64][LDQ]   = (bf16(*)[64][LDQ])(smem + 17408);
  bf16 (*sK)[64][LDQ]   = (bf16(*)[64][LDQ])(smem + 37888);
  bf16 (*sVT)[32][LDVT] = (bf16(*)[32][LDVT])(smem + 58368);
  bf16 (*sP)[64][LDP]   = (bf16(*)[64][LDP])(smem + 17408);  // overlays sQ+sK
  bf16 (*sY)[LDA]       = (bf16(*)[LDA])(smem + 17408);      // overlays sQ
  bf16 (*sH)[LDH]       = (bf16(*)[LDH])(smem + 17408);      // overlays sQ+sK

  const int tid = threadIdx.x;
  const int w   = tid >> 6;   // wave 0..3
  const int l   = tid & 63;
  const int l15 = l & 15;
  const int lhi = l >> 4;     // 0..3

  const int win = blockIdx.x;
  const int b   = win >> 6;
  const int wy  = (win >> 3) & 7;
  const int wx  = win & 7;
  const int rowbase = b * 4096 + wy * 512 + wx * 8; // t = rowbase + (n>>3)*64 + (n&7)

  float yreg[2][4][4];  // post-attention residual, f32, phase4 -> epilogue

  // ---------------- Phase 1: LN1 -> sA (xn1) ----------------
  {
    const int tok = tid >> 2, seg = tid & 3;
    const int t = rowbase + (tok >> 3) * 64 + (tok & 7);
    const float* xr = x + (size_t)t * C_DIM + seg * 32;
    float f[32]; float s = 0.f, s2 = 0.f;
    #pragma unroll
    for (int i = 0; i < 8; i++) {
      f32x4 v = *(const f32x4*)(xr + i * 4);
      #pragma unroll
      for (int j = 0; j < 4; j++) { float a = v[j]; f[i*4+j] = a; s += a; s2 += a*a; }
    }
    s  += __shfl_xor(s, 1);  s  += __shfl_xor(s, 2);
    s2 += __shfl_xor(s2, 1); s2 += __shfl_xor(s2, 2);
    float mu = s * (1.f/128.f);
    float rs = rsqrtf(s2 * (1.f/128.f) - mu*mu + 1e-5f);
    #pragma unroll
    for (int i = 0; i < 4; i++) {
      f32x4 gv0 = *(const f32x4*)(g1  + seg*32 + i*8);
      f32x4 gv1 = *(const f32x4*)(g1  + seg*32 + i*8 + 4);
      f32x4 bv0 = *(const f32x4*)(be1 + seg*32 + i*8);
      f32x4 bv1 = *(const f32x4*)(be1 + seg*32 + i*8 + 4);
      bf16x8 o;
      #pragma unroll
      for (int j = 0; j < 4; j++) {
        o[j]   = (bf16)((f[i*8+j]   - mu) * rs * gv0[j] + bv0[j]);
        o[j+4] = (bf16)((f[i*8+j+4] - mu) * rs * gv1[j] + bv1[j]);
      }
      *(bf16x8*)&sA[tok][seg*32 + i*8] = o;
    }
  }
  __syncthreads();  // BAR1: xn1 ready

  // ---------------- Phase 2: QKV GEMM, SAME-HEAD split: wave w -> q/k/v of head w ----------------
  {
    bf16x8 a[4][4];
    #pragma unroll
    for (int mt = 0; mt < 4; mt++)
      #pragma unroll
      for (int ks = 0; ks < 4; ks++)
        a[mt][ks] = *(const bf16x8*)&sA[mt*16 + l15][ks*32 + lhi*8];
    const float scale = 0.17677669529663687f; // 1/sqrt(32)
    #pragma unroll
    for (int nti = 0; nti < 6; nti++) {
      const int kind = nti >> 1;                 // 0=q 1=k 2=v (compile-time)
      const int d    = (nti & 1) * 16 + l15;     // 0..31 within head
      const int colg = kind * 128 + w * 32 + d;  // global qkv column
      const bf16* wp = Wqkv_t + (size_t)colg * 128 + lhi * 8;
      bf16x8 bw[4];
      #pragma unroll
      for (int ks = 0; ks < 4; ks++) bw[ks] = *(const bf16x8*)(wp + ks * 32);
      const float bias = b_qkv[colg];
      #pragma unroll
      for (int mt = 0; mt < 4; mt++) {
        f32x4 acc = {0.f, 0.f, 0.f, 0.f};
        __builtin_amdgcn_s_setprio(1);
        #pragma unroll
        for (int ks = 0; ks < 4; ks++) acc = mfma16(a[mt][ks], bw[ks], acc);
        __builtin_amdgcn_s_setprio(0);
        #pragma unroll
        for (int r = 0; r < 4; r++) {
          const int token = mt*16 + lhi*4 + r;
          float v = acc[r] + bias;
          if (kind == 0)      sQ[w][token][d] = (bf16)(v * scale);
          else if (kind == 1) sK[w][token][d] = (bf16)v;
          else                sVT[w][d][token] = (bf16)v;
        }
      }
    }
  }
  // NO BARRIER: wave w consumes only its own sQ[w]/sK[w]/sVT[w] writes below.

  // ---------------- Phase 3: attention, wave w = head ----------------
  {
    const int h = w;
    bf16x8 aq[4], bk[4];
    #pragma unroll
    for (int mt = 0; mt < 4; mt++) aq[mt] = *(const bf16x8*)&sQ[h][mt*16 + l15][lhi*8];
    #pragma unroll
    for (int ct = 0; ct < 4; ct++) bk[ct] = *(const bf16x8*)&sK[h][ct*16 + l15][lhi*8];
    f32x4 sc[4][4];
    __builtin_amdgcn_s_setprio(1);
    #pragma unroll
    for (int mt = 0; mt < 4; mt++)
      #pragma unroll
      for (int ct = 0; ct < 4; ct++) {
        f32x4 z = {0.f, 0.f, 0.f, 0.f};
        sc[mt][ct] = mfma16(aq[mt], bk[ct], z);
      }
    __builtin_amdgcn_s_setprio(0);
    // BAR2: all waves completed phase 2 (thus their sA a-frag loads) and their
    // aq/bk loads -> sP may clobber sQ/sK, and O (later) may clobber sA.
    __syncthreads();
    // bias + exp (no max-subtraction; |scores| < 0.4) -> sP UNNORMALIZED;
    // inv deferred to the O-epilogue (removes shfl+rcp+mult from P critical path)
    float inv[4][4];
    #pragma unroll
    for (int mt = 0; mt < 4; mt++) {
      #pragma unroll
      for (int r = 0; r < 4; r++) {
        const int n = mt*16 + lhi*4 + r;
        f32x4 bv = *(const f32x4*)(btabx + (((h*64 + n)*16 + l15) << 2));
        float rv[4]; float sum = 0.f;
        #pragma unroll
        for (int ct = 0; ct < 4; ct++) { rv[ct] = __expf(sc[mt][ct][r] + bv[ct]); sum += rv[ct]; }
        #pragma unroll
        for (int ct = 0; ct < 4; ct++) sP[h][n][ct*16 + l15] = (bf16)rv[ct];
        #pragma unroll
        for (int o = 1; o < 16; o <<= 1) sum += __shfl_xor(sum, o);
        inv[mt][r] = 1.f / sum;
      }
    }
    // PV: O(64x32) = P(64x64) @ V(64x32); B-frags from transposed V
    f32x4 o_[4][2];
    #pragma unroll
    for (int mt = 0; mt < 4; mt++) { f32x4 z = {0.f,0.f,0.f,0.f}; o_[mt][0] = z; o_[mt][1] = z; }
    #pragma unroll
    for (int ks = 0; ks < 2; ks++) {
      bf16x8 ap[4], bvv[2];
      #pragma unroll
      for (int mt = 0; mt < 4; mt++) ap[mt] = *(const bf16x8*)&sP[h][mt*16 + l15][ks*32 + lhi*8];
      #pragma unroll
      for (int c2 = 0; c2 < 2; c2++) bvv[c2] = *(const bf16x8*)&sVT[h][c2*16 + l15][ks*32 + lhi*8];
      __builtin_amdgcn_s_setprio(1);
      #pragma unroll
      for (int mt = 0; mt < 4; mt++)
        #pragma unroll
        for (int c2 = 0; c2 < 2; c2++) o_[mt][c2] = mfma16(ap[mt], bvv[c2], o_[mt][c2]);
      __builtin_amdgcn_s_setprio(0);
    }
    #pragma unroll
    for (int mt = 0; mt < 4; mt++)
      #pragma unroll
      for (int c2 = 0; c2 < 2; c2++)
        #pragma unroll
        for (int r = 0; r < 4; r++)
          sA[mt*16 + lhi*4 + r][h*32 + c2*16 + l15] = (bf16)(o_[mt][c2][r] * inv[mt][r]);
  }
  __syncthreads();  // BAR3: O ready

  // ---------------- Phase 4: out-proj + shortcut -> sY + yreg ----------------
  {
    // batch-issue all 32 x-residual loads FIRST (latency drains under weight
    // loads + MFMAs below; yreg already budgeted, 0 extra regs)
    #pragma unroll
    for (int nto = 0; nto < 2; nto++) {
      const int col = (w*2 + nto) * 16 + l15;
      #pragma unroll
      for (int mt = 0; mt < 4; mt++)
        #pragma unroll
        for (int r = 0; r < 4; r++) {
          const int token = mt*16 + lhi*4 + r;
          const int t = rowbase + (token >> 3) * 64 + (token & 7);
          yreg[nto][mt][r] = x[(size_t)t * C_DIM + col];
        }
    }
    bf16x8 a[4][4];
    #pragma unroll
    for (int mt = 0; mt < 4; mt++)
      #pragma unroll
      for (int ks = 0; ks < 4; ks++)
        a[mt][ks] = *(const bf16x8*)&sA[mt*16 + l15][ks*32 + lhi*8];
    #pragma unroll
    for (int nto = 0; nto < 2; nto++) {
      const int col = (w*2 + nto) * 16 + l15;
      const bf16* wp = Wout_t + (size_t)col * 128 + lhi * 8;
      bf16x8 bw[4];
      #pragma unroll
      for (int ks = 0; ks < 4; ks++) bw[ks] = *(const bf16x8*)(wp + ks * 32);
      const float bo = b_out[col];
      #pragma unroll
      for (int mt = 0; mt < 4; mt++) {
        f32x4 acc = {0.f, 0.f, 0.f, 0.f};
        __builtin_amdgcn_s_setprio(1);
        #pragma unroll
        for (int ks = 0; ks < 4; ks++) acc = mfma16(a[mt][ks], bw[ks], acc);
        __builtin_amdgcn_s_setprio(0);
        #pragma unroll
        for (int r = 0; r < 4; r++) {
          const int token = mt*16 + lhi*4 + r;
          float v = acc[r] + bo + yreg[nto][mt][r];
          yreg[nto][mt][r] = v;
          sY[token][col] = (bf16)v;
        }
      }
    }
  }
  __syncthreads();  // BAR4: sY ready

  // ---------------- Phase 5: LN2 (sY -> sA as xn2) ----------------
  {
    const int tok = tid >> 2, seg = tid & 3;
    float f[32]; float s = 0.f, s2 = 0.f;
    #pragma unroll
    for (int i = 0; i < 4; i++) {
      bf16x8 v = *(const bf16x8*)&sY[tok][seg*32 + i*8];
      #pragma unroll
      for (int j = 0; j < 8; j++) { float a = (float)v[j]; f[i*8+j] = a; s += a; s2 += a*a; }
    }
    s  += __shfl_xor(s, 1);  s  += __shfl_xor(s, 2);
    s2 += __shfl_xor(s2, 1); s2 += __shfl_xor(s2, 2);
    float mu = s * (1.f/128.f);
    float rs = rsqrtf(s2 * (1.f/128.f) - mu*mu + 1e-5f);
    #pragma unroll
    for (int i = 0; i < 4; i++) {
      f32x4 gv0 = *(const f32x4*)(g2  + seg*32 + i*8);
      f32x4 gv1 = *(const f32x4*)(g2  + seg*32 + i*8 + 4);
      f32x4 bv0 = *(const f32x4*)(be2 + seg*32 + i*8);
      f32x4 bv1 = *(const f32x4*)(be2 + seg*32 + i*8 + 4);
      bf16x8 o;
      #pragma unroll
      for (int j = 0; j < 4; j++) {
        o[j]   = (bf16)((f[i*8+j]   - mu) * rs * gv0[j] + bv0[j]);
        o[j+4] = (bf16)((f[i*8+j+4] - mu) * rs * gv1[j] + bv1[j]);
      }
      *(bf16x8*)&sA[tok][seg*32 + i*8] = o;
    }
  }
  __syncthreads();  // BAR5: xn2 ready

  // ---------------- Phase 6: MLP (FC1+GELU -> sH halves, FC2 rolling-prefetch) ----------------
  {
    bf16x8 a[4][4];
    #pragma unroll
    for (int mt = 0; mt < 4; mt++)
      #pragma unroll
      for (int ks = 0; ks < 4; ks++)
        a[mt][ks] = *(const bf16x8*)&sA[mt*16 + l15][ks*32 + lhi*8];
    f32x4 accF[2][4];
    #pragma unroll
    for (int i = 0; i < 2; i++)
      #pragma unroll
      for (int mt = 0; mt < 4; mt++) { f32x4 z = {0.f,0.f,0.f,0.f}; accF[i][mt] = z; }

    #pragma unroll
    for (int hf = 0; hf < 2; hf++) {
      // FC1 quarter: wave w owns local hidden cols [w*64, w*64+64) of this half
      #pragma unroll
      for (int nti = 0; nti < 4; nti++) {
        const int ntg    = hf*16 + w*4 + nti;          // global hidden tile 0..31
        const int colh   = ntg*16 + l15;               // global hidden col
        const int colloc = (w*4 + nti)*16 + l15;       // col within sH half
        const bf16* wp = Wfc1_t + (size_t)colh * 128 + lhi * 8;
        bf16x8 bw[4];
        #pragma unroll
        for (int ks = 0; ks < 4; ks++) bw[ks] = *(const bf16x8*)(wp + ks * 32);
        const float bb = b_fc1[colh];
        #pragma unroll
        for (int mt = 0; mt < 4; mt++) {
          f32x4 acc = {0.f, 0.f, 0.f, 0.f};
          __builtin_amdgcn_s_setprio(1);
          #pragma unroll
          for (int ks = 0; ks < 4; ks++) acc = mfma16(a[mt][ks], bw[ks], acc);
          __builtin_amdgcn_s_setprio(0);
          #pragma unroll
          for (int r = 0; r < 4; r++) {
            float v = acc[r] + bb;
            // GELU via sigmoid form: v*sigma(1.702v); |err| < ~5e-3 for |v|<1.5
            float g = v / (1.f + __expf(-1.702f * v));
            sH[mt*16 + lhi*4 + r][colloc] = (bf16)g;
          }
        }
      }
      __syncthreads();
      // FC2 partial over this half's 256 hidden dims; 1-deep rolling bw2 prefetch
      bf16x8 bw2[2];
      #pragma unroll
      for (int nto = 0; nto < 2; nto++)
        bw2[nto] = *(const bf16x8*)(Wfc2_t + (size_t)((w*2 + nto)*16 + l15) * 512 + hf*256 + lhi*8);
      #pragma unroll
      for (int ks = 0; ks < 8; ks++) {
        bf16x8 bw2n[2];
        if (ks < 7) {
          #pragma unroll
          for (int nto = 0; nto < 2; nto++)
            bw2n[nto] = *(const bf16x8*)(Wfc2_t + (size_t)((w*2 + nto)*16 + l15) * 512 + hf*256 + (ks+1)*32 + lhi*8);
        }
        bf16x8 ah[4];
        #pragma unroll
        for (int mt = 0; mt < 4; mt++) ah[mt] = *(const bf16x8*)&sH[mt*16 + l15][ks*32 + lhi*8];
        __builtin_amdgcn_s_setprio(1);
        #pragma unroll
        for (int nto = 0; nto < 2; nto++)
          #pragma unroll
          for (int mt = 0; mt < 4; mt++) accF[nto][mt] = mfma16(ah[mt], bw2[nto], accF[nto][mt]);
        __builtin_amdgcn_s_setprio(0);
        if (ks < 7) { bw2[0] = bw2n[0]; bw2[1] = bw2n[1]; }
      }
      __syncthreads();
    }
    // epilogue: + b_fc2 + y -> out (f32)
    #pragma unroll
    for (int nto = 0; nto < 2; nto++) {
      const int col = (w*2 + nto)*16 + l15;
      const float bb = b_fc2[col];
      #pragma unroll
      for (int mt = 0; mt < 4; mt++)
        #pragma unroll
        for (int r = 0; r < 4; r++) {
          const int token = mt*16 + lhi*4 + r;
          const int t = rowbase + (token >> 3) * 64 + (token & 7);
          out[(size_t)t * C_DIM + col] = accF[nto][mt][r] + bb + yreg[nto][mt][r];
        }
    }
  }
}

// Transpose f32 weights -> bf16 (W_t[n][k] = W[k][n]) and expand the rel-pos
// bias table to btabx[h][n][l15][ct] = btab[idx(n, ct*16+l15)*4 + h]  (f32)
__global__ void prep_transpose(
    const float* __restrict__ Wqkv, const float* __restrict__ Wout,
    const float* __restrict__ Wfc1, const float* __restrict__ Wfc2,
    const float* __restrict__ btab,
    bf16* __restrict__ Wqkv_t, bf16* __restrict__ Wout_t,
    bf16* __restrict__ Wfc1_t, bf16* __restrict__ Wfc2_t,
    float* __restrict__ btabx)
{
  int i = blockIdx.x * 256 + threadIdx.x;
  if (i < 49152) { int n = i >> 7, k = i & 127; Wqkv_t[i] = (bf16)Wqkv[k*384 + n]; return; }
  i -= 49152;
  if (i < 16384) { int n = i >> 7, k = i & 127; Wout_t[i] = (bf16)Wout[k*128 + n]; return; }
  i -= 16384;
  if (i < 65536) { int n = i >> 7, k = i & 127; Wfc1_t[i] = (bf16)Wfc1[k*512 + n]; return; }
  i -= 65536;
  if (i < 65536) { int n = i >> 9, k = i & 511; Wfc2_t[i] = (bf16)Wfc2[k*128 + n]; return; }
  i -= 65536;
  if (i < 16384) {
    int ct  = i & 3;
    int l15 = (i >> 2) & 15;
    int n   = (i >> 6) & 63;
    int h   = i >> 12;
    int m = ct * 16 + l15;
    int nr = n >> 3, nc = n & 7, mr = m >> 3, mc = m & 7;
    int idx = (nr - mr + 7) * 15 + (nc - mc + 7);
    btabx[i] = btab[idx * 4 + h];
  }
}

extern "C" void kernel_launch(void* const* d_in, const int* in_sizes, int n_in,
                              void* d_out, int out_size, void* d_ws, size_t ws_size,
                              hipStream_t stream)
{
  const float* x    = (const float*)d_in[0];
  const float* Wqkv = (const float*)d_in[1];
  const float* bqkv = (const float*)d_in[2];
  const float* Wout = (const float*)d_in[3];
  const float* bout = (const float*)d_in[4];
  const float* btab = (const float*)d_in[5];
  const float* g1   = (const float*)d_in[6];
  const float* be1  = (const float*)d_in[7];
  const float* g2   = (const float*)d_in[8];
  const float* be2  = (const float*)d_in[9];
  const float* Wfc1 = (const float*)d_in[10];
  const float* bfc1 = (const float*)d_in[11];
  const float* Wfc2 = (const float*)d_in[12];
  const float* bfc2 = (const float*)d_in[13];
  // d_in[14]=H, d_in[15]=W (fixed 64)

  bf16* ws = (bf16*)d_ws;
  bf16* Wqkv_t = ws;            // 384x128
  bf16* Wout_t = ws + 49152;    // 128x128
  bf16* Wfc1_t = ws + 65536;    // 512x128
  bf16* Wfc2_t = ws + 131072;   // 128x512
  float* btabx = (float*)(ws + 196608);  // 4*64*16*4 f32 = 64KB

  prep_transpose<<<832, 256, 0, stream>>>(Wqkv, Wout, Wfc1, Wfc2, btab,
                                          Wqkv_t, Wout_t, Wfc1_t, Wfc2_t, btabx);

  const int B = in_sizes[0] / (4096 * 128);
  swin_fused<<<dim3(B * 64), 256, 0, stream>>>(
      x, Wqkv_t, bqkv, Wout_t, bout, btabx, g1, be1, g2, be2,
      Wfc1_t, bfc1, Wfc2_t, bfc2, (float*)d_out);
}

// Round 18
// 165.039 us; speedup vs baseline: 1.0356x; 1.0356x over previous
//
#include <hip/hip_runtime.h>
#include <hip/hip_bf16.h>

typedef __bf16 bf16;
typedef __bf16 bf16x8 __attribute__((ext_vector_type(8)));
typedef float f32x4 __attribute__((ext_vector_type(4)));

#define C_DIM 128
#define LDA 136   // sA/sY row stride (bf16 elems)
#define LDQ 40    // q/k row stride
#define LDVT 72   // vT row stride
#define LDP 72    // P row stride
#define LDH 264   // h-half row stride

__device__ __forceinline__ f32x4 mfma16(bf16x8 a, bf16x8 b, f32x4 c) {
  return __builtin_amdgcn_mfma_f32_16x16x32_bf16(a, b, c, 0, 0, 0);
}

// r18 = r16 (166.6us best) + DEFERRED SOFTMAX NORM ONLY (isolating r17's A/B;
// setprio removed — guide m190 shows it is negative on lockstep GEMM phases):
//   sP holds unnormalized e=exp(s+bias) (<= e^0.8~2.2, bf16-safe); the 16-lane
//   shfl reduce + rcp overlap PV fragment loads/MFMAs; inv applied at O-store
//   (row n = mt*16+lhi*4+r identical on both sides -> mathematically exact).
// r15 lesson: never shrink M below 64 (weight-frag reuse). r14: packed-store
// transposes add bank conflicts. r11/r12: declared occupancy >=3 always
// under-allocates VGPR ~2x -> spills. (256,2) is the only clean codegen config.
//
// LDS layout (76800 B, 2 blocks/CU at 256 threads):
//   sA  @ 0      : 64x136 bf16 = 17408   xn1 -> O(attn concat) -> xn2
//   R1  @ 17408  : sQ[4][64][40]+sK[4][64][40] -> sP[4][64][72] -> sY -> sH[64][264]
//   sVT @ 58368  : 4x32x72
// Retained: same-head QKV (no P2->P3 barrier), compile-time kind, no-max softmax
// (|scores|<0.4 by construction), sigmoid-GELU, launch_bounds(256,2),
// batch-issued x residual loads, rolling FC2 prefetch.

__global__ __launch_bounds__(256, 2) void swin_fused(
    const float* __restrict__ x,
    const bf16*  __restrict__ Wqkv_t, const float* __restrict__ b_qkv,
    const bf16*  __restrict__ Wout_t, const float* __restrict__ b_out,
    const float* __restrict__ btabx,
    const float* __restrict__ g1, const float* __restrict__ be1,
    const float* __restrict__ g2, const float* __restrict__ be2,
    const bf16*  __restrict__ Wfc1_t, const float* __restrict__ b_fc1,
    const bf16*  __restrict__ Wfc2_t, const float* __restrict__ b_fc2,
    float* __restrict__ out)
{
  __shared__ __attribute__((aligned(16))) char smem[76800];
  bf16 (*sA)[LDA]       = (bf16(*)[LDA])(smem);
  bf16 (*sQ)[64][LDQ]   = (bf16(*)[64][LDQ])(smem + 17408);
  bf16 (*sK)[64][LDQ]   = (bf16(*)[64][LDQ])(smem + 37888);
  bf16 (*sVT)[32][LDVT] = (bf16(*)[32][LDVT])(smem + 58368);
  bf16 (*sP)[64][LDP]   = (bf16(*)[64][LDP])(smem + 17408);  // overlays sQ+sK
  bf16 (*sY)[LDA]       = (bf16(*)[LDA])(smem + 17408);      // overlays sQ
  bf16 (*sH)[LDH]       = (bf16(*)[LDH])(smem + 17408);      // overlays sQ+sK

  const int tid = threadIdx.x;
  const int w   = tid >> 6;   // wave 0..3
  const int l   = tid & 63;
  const int l15 = l & 15;
  const int lhi = l >> 4;     // 0..3

  const int win = blockIdx.x;
  const int b   = win >> 6;
  const int wy  = (win >> 3) & 7;
  const int wx  = win & 7;
  const int rowbase = b * 4096 + wy * 512 + wx * 8; // t = rowbase + (n>>3)*64 + (n&7)

  float yreg[2][4][4];  // post-attention residual, f32, phase4 -> epilogue

  // ---------------- Phase 1: LN1 -> sA (xn1) ----------------
  {
    const int tok = tid >> 2, seg = tid & 3;
    const int t = rowbase + (tok >> 3) * 64 + (tok & 7);
    const float* xr = x + (size_t)t * C_DIM + seg * 32;
    float f[32]; float s = 0.f, s2 = 0.f;
    #pragma unroll
    for (int i = 0; i < 8; i++) {
      f32x4 v = *(const f32x4*)(xr + i * 4);
      #pragma unroll
      for (int j = 0; j < 4; j++) { float a = v[j]; f[i*4+j] = a; s += a; s2 += a*a; }
    }
    s  += __shfl_xor(s, 1);  s  += __shfl_xor(s, 2);
    s2 += __shfl_xor(s2, 1); s2 += __shfl_xor(s2, 2);
    float mu = s * (1.f/128.f);
    float rs = rsqrtf(s2 * (1.f/128.f) - mu*mu + 1e-5f);
    #pragma unroll
    for (int i = 0; i < 4; i++) {
      f32x4 gv0 = *(const f32x4*)(g1  + seg*32 + i*8);
      f32x4 gv1 = *(const f32x4*)(g1  + seg*32 + i*8 + 4);
      f32x4 bv0 = *(const f32x4*)(be1 + seg*32 + i*8);
      f32x4 bv1 = *(const f32x4*)(be1 + seg*32 + i*8 + 4);
      bf16x8 o;
      #pragma unroll
      for (int j = 0; j < 4; j++) {
        o[j]   = (bf16)((f[i*8+j]   - mu) * rs * gv0[j] + bv0[j]);
        o[j+4] = (bf16)((f[i*8+j+4] - mu) * rs * gv1[j] + bv1[j]);
      }
      *(bf16x8*)&sA[tok][seg*32 + i*8] = o;
    }
  }
  __syncthreads();  // BAR1: xn1 ready

  // ---------------- Phase 2: QKV GEMM, SAME-HEAD split: wave w -> q/k/v of head w ----------------
  {
    bf16x8 a[4][4];
    #pragma unroll
    for (int mt = 0; mt < 4; mt++)
      #pragma unroll
      for (int ks = 0; ks < 4; ks++)
        a[mt][ks] = *(const bf16x8*)&sA[mt*16 + l15][ks*32 + lhi*8];
    const float scale = 0.17677669529663687f; // 1/sqrt(32)
    #pragma unroll
    for (int nti = 0; nti < 6; nti++) {
      const int kind = nti >> 1;                 // 0=q 1=k 2=v (compile-time)
      const int d    = (nti & 1) * 16 + l15;     // 0..31 within head
      const int colg = kind * 128 + w * 32 + d;  // global qkv column
      const bf16* wp = Wqkv_t + (size_t)colg * 128 + lhi * 8;
      bf16x8 bw[4];
      #pragma unroll
      for (int ks = 0; ks < 4; ks++) bw[ks] = *(const bf16x8*)(wp + ks * 32);
      const float bias = b_qkv[colg];
      #pragma unroll
      for (int mt = 0; mt < 4; mt++) {
        f32x4 acc = {0.f, 0.f, 0.f, 0.f};
        #pragma unroll
        for (int ks = 0; ks < 4; ks++) acc = mfma16(a[mt][ks], bw[ks], acc);
        #pragma unroll
        for (int r = 0; r < 4; r++) {
          const int token = mt*16 + lhi*4 + r;
          float v = acc[r] + bias;
          if (kind == 0)      sQ[w][token][d] = (bf16)(v * scale);
          else if (kind == 1) sK[w][token][d] = (bf16)v;
          else                sVT[w][d][token] = (bf16)v;
        }
      }
    }
  }
  // NO BARRIER: wave w consumes only its own sQ[w]/sK[w]/sVT[w] writes below.

  // ---------------- Phase 3: attention, wave w = head ----------------
  {
    const int h = w;
    bf16x8 aq[4], bk[4];
    #pragma unroll
    for (int mt = 0; mt < 4; mt++) aq[mt] = *(const bf16x8*)&sQ[h][mt*16 + l15][lhi*8];
    #pragma unroll
    for (int ct = 0; ct < 4; ct++) bk[ct] = *(const bf16x8*)&sK[h][ct*16 + l15][lhi*8];
    f32x4 sc[4][4];
    #pragma unroll
    for (int mt = 0; mt < 4; mt++)
      #pragma unroll
      for (int ct = 0; ct < 4; ct++) {
        f32x4 z = {0.f, 0.f, 0.f, 0.f};
        sc[mt][ct] = mfma16(aq[mt], bk[ct], z);
      }
    // BAR2: all waves completed phase 2 (thus their sA a-frag loads) and their
    // aq/bk loads -> sP may clobber sQ/sK, and O (later) may clobber sA.
    __syncthreads();
    // bias + exp (no max-subtraction; |scores| < 0.4) -> sP UNNORMALIZED;
    // the shfl reduce + rcp overlap the PV fragment loads/MFMAs below.
    float inv[4][4];
    #pragma unroll
    for (int mt = 0; mt < 4; mt++) {
      #pragma unroll
      for (int r = 0; r < 4; r++) {
        const int n = mt*16 + lhi*4 + r;
        f32x4 bv = *(const f32x4*)(btabx + (((h*64 + n)*16 + l15) << 2));
        float rv[4]; float sum = 0.f;
        #pragma unroll
        for (int ct = 0; ct < 4; ct++) { rv[ct] = __expf(sc[mt][ct][r] + bv[ct]); sum += rv[ct]; }
        #pragma unroll
        for (int ct = 0; ct < 4; ct++) sP[h][n][ct*16 + l15] = (bf16)rv[ct];
        #pragma unroll
        for (int o = 1; o < 16; o <<= 1) sum += __shfl_xor(sum, o);
        inv[mt][r] = 1.f / sum;
      }
    }
    // PV: O(64x32) = P(64x64) @ V(64x32); B-frags from transposed V
    f32x4 o_[4][2];
    #pragma unroll
    for (int mt = 0; mt < 4; mt++) { f32x4 z = {0.f,0.f,0.f,0.f}; o_[mt][0] = z; o_[mt][1] = z; }
    #pragma unroll
    for (int ks = 0; ks < 2; ks++) {
      bf16x8 ap[4], bvv[2];
      #pragma unroll
      for (int mt = 0; mt < 4; mt++) ap[mt] = *(const bf16x8*)&sP[h][mt*16 + l15][ks*32 + lhi*8];
      #pragma unroll
      for (int c2 = 0; c2 < 2; c2++) bvv[c2] = *(const bf16x8*)&sVT[h][c2*16 + l15][ks*32 + lhi*8];
      #pragma unroll
      for (int mt = 0; mt < 4; mt++)
        #pragma unroll
        for (int c2 = 0; c2 < 2; c2++) o_[mt][c2] = mfma16(ap[mt], bvv[c2], o_[mt][c2]);
    }
    #pragma unroll
    for (int mt = 0; mt < 4; mt++)
      #pragma unroll
      for (int c2 = 0; c2 < 2; c2++)
        #pragma unroll
        for (int r = 0; r < 4; r++)
          sA[mt*16 + lhi*4 + r][h*32 + c2*16 + l15] = (bf16)(o_[mt][c2][r] * inv[mt][r]);
  }
  __syncthreads();  // BAR3: O ready

  // ---------------- Phase 4: out-proj + shortcut -> sY + yreg ----------------
  {
    // batch-issue all 32 x-residual loads FIRST (latency drains under weight
    // loads + MFMAs below; yreg already budgeted, 0 extra regs)
    #pragma unroll
    for (int nto = 0; nto < 2; nto++) {
      const int col = (w*2 + nto) * 16 + l15;
      #pragma unroll
      for (int mt = 0; mt < 4; mt++)
        #pragma unroll
        for (int r = 0; r < 4; r++) {
          const int token = mt*16 + lhi*4 + r;
          const int t = rowbase + (token >> 3) * 64 + (token & 7);
          yreg[nto][mt][r] = x[(size_t)t * C_DIM + col];
        }
    }
    bf16x8 a[4][4];
    #pragma unroll
    for (int mt = 0; mt < 4; mt++)
      #pragma unroll
      for (int ks = 0; ks < 4; ks++)
        a[mt][ks] = *(const bf16x8*)&sA[mt*16 + l15][ks*32 + lhi*8];
    #pragma unroll
    for (int nto = 0; nto < 2; nto++) {
      const int col = (w*2 + nto) * 16 + l15;
      const bf16* wp = Wout_t + (size_t)col * 128 + lhi * 8;
      bf16x8 bw[4];
      #pragma unroll
      for (int ks = 0; ks < 4; ks++) bw[ks] = *(const bf16x8*)(wp + ks * 32);
      const float bo = b_out[col];
      #pragma unroll
      for (int mt = 0; mt < 4; mt++) {
        f32x4 acc = {0.f, 0.f, 0.f, 0.f};
        #pragma unroll
        for (int ks = 0; ks < 4; ks++) acc = mfma16(a[mt][ks], bw[ks], acc);
        #pragma unroll
        for (int r = 0; r < 4; r++) {
          const int token = mt*16 + lhi*4 + r;
          float v = acc[r] + bo + yreg[nto][mt][r];
          yreg[nto][mt][r] = v;
          sY[token][col] = (bf16)v;
        }
      }
    }
  }
  __syncthreads();  // BAR4: sY ready

  // ---------------- Phase 5: LN2 (sY -> sA as xn2) ----------------
  {
    const int tok = tid >> 2, seg = tid & 3;
    float f[32]; float s = 0.f, s2 = 0.f;
    #pragma unroll
    for (int i = 0; i < 4; i++) {
      bf16x8 v = *(const bf16x8*)&sY[tok][seg*32 + i*8];
      #pragma unroll
      for (int j = 0; j < 8; j++) { float a = (float)v[j]; f[i*8+j] = a; s += a; s2 += a*a; }
    }
    s  += __shfl_xor(s, 1);  s  += __shfl_xor(s, 2);
    s2 += __shfl_xor(s2, 1); s2 += __shfl_xor(s2, 2);
    float mu = s * (1.f/128.f);
    float rs = rsqrtf(s2 * (1.f/128.f) - mu*mu + 1e-5f);
    #pragma unroll
    for (int i = 0; i < 4; i++) {
      f32x4 gv0 = *(const f32x4*)(g2  + seg*32 + i*8);
      f32x4 gv1 = *(const f32x4*)(g2  + seg*32 + i*8 + 4);
      f32x4 bv0 = *(const f32x4*)(be2 + seg*32 + i*8);
      f32x4 bv1 = *(const f32x4*)(be2 + seg*32 + i*8 + 4);
      bf16x8 o;
      #pragma unroll
      for (int j = 0; j < 4; j++) {
        o[j]   = (bf16)((f[i*8+j]   - mu) * rs * gv0[j] + bv0[j]);
        o[j+4] = (bf16)((f[i*8+j+4] - mu) * rs * gv1[j] + bv1[j]);
      }
      *(bf16x8*)&sA[tok][seg*32 + i*8] = o;
    }
  }
  __syncthreads();  // BAR5: xn2 ready

  // ---------------- Phase 6: MLP (FC1+GELU -> sH halves, FC2 rolling-prefetch) ----------------
  {
    bf16x8 a[4][4];
    #pragma unroll
    for (int mt = 0; mt < 4; mt++)
      #pragma unroll
      for (int ks = 0; ks < 4; ks++)
        a[mt][ks] = *(const bf16x8*)&sA[mt*16 + l15][ks*32 + lhi*8];
    f32x4 accF[2][4];
    #pragma unroll
    for (int i = 0; i < 2; i++)
      #pragma unroll
      for (int mt = 0; mt < 4; mt++) { f32x4 z = {0.f,0.f,0.f,0.f}; accF[i][mt] = z; }

    #pragma unroll
    for (int hf = 0; hf < 2; hf++) {
      // FC1 quarter: wave w owns local hidden cols [w*64, w*64+64) of this half
      #pragma unroll
      for (int nti = 0; nti < 4; nti++) {
        const int ntg    = hf*16 + w*4 + nti;          // global hidden tile 0..31
        const int colh   = ntg*16 + l15;               // global hidden col
        const int colloc = (w*4 + nti)*16 + l15;       // col within sH half
        const bf16* wp = Wfc1_t + (size_t)colh * 128 + lhi * 8;
        bf16x8 bw[4];
        #pragma unroll
        for (int ks = 0; ks < 4; ks++) bw[ks] = *(const bf16x8*)(wp + ks * 32);
        const float bb = b_fc1[colh];
        #pragma unroll
        for (int mt = 0; mt < 4; mt++) {
          f32x4 acc = {0.f, 0.f, 0.f, 0.f};
          #pragma unroll
          for (int ks = 0; ks < 4; ks++) acc = mfma16(a[mt][ks], bw[ks], acc);
          #pragma unroll
          for (int r = 0; r < 4; r++) {
            float v = acc[r] + bb;
            // GELU via sigmoid form: v*sigma(1.702v); |err| < ~5e-3 for |v|<1.5
            float g = v / (1.f + __expf(-1.702f * v));
            sH[mt*16 + lhi*4 + r][colloc] = (bf16)g;
          }
        }
      }
      __syncthreads();
      // FC2 partial over this half's 256 hidden dims; 1-deep rolling bw2 prefetch
      bf16x8 bw2[2];
      #pragma unroll
      for (int nto = 0; nto < 2; nto++)
        bw2[nto] = *(const bf16x8*)(Wfc2_t + (size_t)((w*2 + nto)*16 + l15) * 512 + hf*256 + lhi*8);
      #pragma unroll
      for (int ks = 0; ks < 8; ks++) {
        bf16x8 bw2n[2];
        if (ks < 7) {
          #pragma unroll
          for (int nto = 0; nto < 2; nto++)
            bw2n[nto] = *(const bf16x8*)(Wfc2_t + (size_t)((w*2 + nto)*16 + l15) * 512 + hf*256 + (ks+1)*32 + lhi*8);
        }
        bf16x8 ah[4];
        #pragma unroll
        for (int mt = 0; mt < 4; mt++) ah[mt] = *(const bf16x8*)&sH[mt*16 + l15][ks*32 + lhi*8];
        #pragma unroll
        for (int nto = 0; nto < 2; nto++)
          #pragma unroll
          for (int mt = 0; mt < 4; mt++) accF[nto][mt] = mfma16(ah[mt], bw2[nto], accF[nto][mt]);
        if (ks < 7) { bw2[0] = bw2n[0]; bw2[1] = bw2n[1]; }
      }
      __syncthreads();
    }
    // epilogue: + b_fc2 + y -> out (f32)
    #pragma unroll
    for (int nto = 0; nto < 2; nto++) {
      const int col = (w*2 + nto)*16 + l15;
      const float bb = b_fc2[col];
      #pragma unroll
      for (int mt = 0; mt < 4; mt++)
        #pragma unroll
        for (int r = 0; r < 4; r++) {
          const int token = mt*16 + lhi*4 + r;
          const int t = rowbase + (token >> 3) * 64 + (token & 7);
          out[(size_t)t * C_DIM + col] = accF[nto][mt][r] + bb + yreg[nto][mt][r];
        }
    }
  }
}

// Transpose f32 weights -> bf16 (W_t[n][k] = W[k][n]) and expand the rel-pos
// bias table to btabx[h][n][l15][ct] = btab[idx(n, ct*16+l15)*4 + h]  (f32)
__global__ void prep_transpose(
    const float* __restrict__ Wqkv, const float* __restrict__ Wout,
    const float* __restrict__ Wfc1, const float* __restrict__ Wfc2,
    const float* __restrict__ btab,
    bf16* __restrict__ Wqkv_t, bf16* __restrict__ Wout_t,
    bf16* __restrict__ Wfc1_t, bf16* __restrict__ Wfc2_t,
    float* __restrict__ btabx)
{
  int i = blockIdx.x * 256 + threadIdx.x;
  if (i < 49152) { int n = i >> 7, k = i & 127; Wqkv_t[i] = (bf16)Wqkv[k*384 + n]; return; }
  i -= 49152;
  if (i < 16384) { int n = i >> 7, k = i & 127; Wout_t[i] = (bf16)Wout[k*128 + n]; return; }
  i -= 16384;
  if (i < 65536) { int n = i >> 7, k = i & 127; Wfc1_t[i] = (bf16)Wfc1[k*512 + n]; return; }
  i -= 65536;
  if (i < 65536) { int n = i >> 9, k = i & 511; Wfc2_t[i] = (bf16)Wfc2[k*128 + n]; return; }
  i -= 65536;
  if (i < 16384) {
    int ct  = i & 3;
    int l15 = (i >> 2) & 15;
    int n   = (i >> 6) & 63;
    int h   = i >> 12;
    int m = ct * 16 + l15;
    int nr = n >> 3, nc = n & 7, mr = m >> 3, mc = m & 7;
    int idx = (nr - mr + 7) * 15 + (nc - mc + 7);
    btabx[i] = btab[idx * 4 + h];
  }
}

extern "C" void kernel_launch(void* const* d_in, const int* in_sizes, int n_in,
                              void* d_out, int out_size, void* d_ws, size_t ws_size,
                              hipStream_t stream)
{
  const float* x    = (const float*)d_in[0];
  const float* Wqkv = (const float*)d_in[1];
  const float* bqkv = (const float*)d_in[2];
  const float* Wout = (const float*)d_in[3];
  const float* bout = (const float*)d_in[4];
  const float* btab = (const float*)d_in[5];
  const float* g1   = (const float*)d_in[6];
  const float* be1  = (const float*)d_in[7];
  const float* g2   = (const float*)d_in[8];
  const float* be2  = (const float*)d_in[9];
  const float* Wfc1 = (const float*)d_in[10];
  const float* bfc1 = (const float*)d_in[11];
  const float* Wfc2 = (const float*)d_in[12];
  const float* bfc2 = (const float*)d_in[13];
  // d_in[14]=H, d_in[15]=W (fixed 64)

  bf16* ws = (bf16*)d_ws;
  bf16* Wqkv_t = ws;            // 384x128
  bf16* Wout_t = ws + 49152;    // 128x128
  bf16* Wfc1_t = ws + 65536;    // 512x128
  bf16* Wfc2_t = ws + 131072;   // 128x512
  float* btabx = (float*)(ws + 196608);  // 4*64*16*4 f32 = 64KB

  prep_transpose<<<832, 256, 0, stream>>>(Wqkv, Wout, Wfc1, Wfc2, btab,
                                          Wqkv_t, Wout_t, Wfc1_t, Wfc2_t, btabx);

  const int B = in_sizes[0] / (4096 * 128);
  swin_fused<<<dim3(B * 64), 256, 0, stream>>>(
      x, Wqkv_t, bqkv, Wout_t, bout, btabx, g1, be1, g2, be2,
      Wfc1_t, bfc1, Wfc2_t, bfc2, (float*)d_out);
}